// Round 1
// baseline (431.856 us; speedup 1.0000x reference)
//
#include <hip/hip_runtime.h>
#include <stdint.h>

typedef unsigned short u16;
typedef unsigned int   u32;
typedef __attribute__((ext_vector_type(8))) short short8;
typedef __attribute__((ext_vector_type(4))) short short4v;
typedef __attribute__((ext_vector_type(4))) float float4v;
typedef __attribute__((ext_vector_type(4))) u32   uint4v;

#define B_  4
#define T_  4096
#define C_  1024
#define H_  16
#define G_  16
#define GS_ 256
#define NC_ 64

static __device__ __forceinline__ u16 f2bf(float f){
  union{float f; u32 u;} c; c.f = f;
  return (u16)((c.u + 0x7fffu + ((c.u >> 16) & 1u)) >> 16);
}
static __device__ __forceinline__ float bf2f(u16 u){
  union{u32 u; float f;} c; c.u = ((u32)u) << 16; return c.f;
}
static __device__ __forceinline__ void gload16(const void* g, void* l){
  __builtin_amdgcn_global_load_lds((__attribute__((address_space(1))) void*)g,
                                   (__attribute__((address_space(3))) void*)l, 16, 0, 0);
}

// ---------------- fp32 -> bf16 convert ----------------
__global__ __launch_bounds__(256) void f2b_kernel(const float* __restrict__ s,
                                                  u16* __restrict__ d, int n4){
  int i = blockIdx.x * 256 + threadIdx.x;
  if(i >= n4) return;
  float4v v = *(const float4v*)(s + (size_t)i * 4);
  short4v o;
  o.x = (short)f2bf(v.x); o.y = (short)f2bf(v.y);
  o.z = (short)f2bf(v.z); o.w = (short)f2bf(v.w);
  *(short4v*)(d + (size_t)i * 4) = o;
}

// ---------------- sinusoidal table S[pos][d], pos<316, d<64 ----------------
__global__ void stab_kernel(float* __restrict__ S){
  int pos = blockIdx.x, d = threadIdx.x;
  int j = d >> 1;
  float div = expf((float)(2 * j) * (-0.14391156831212787f)); // -ln(10000)/64
  float ang = (float)pos * div;
  S[pos * 64 + d] = (d & 1) ? cosf(ang) : sinf(ang);
}

// ---------------- GEMM: C[M,N] = A[M,K] * B[N,K]^T + bias ----------------
// m97 structure: 128x128 tile, BK=64, global_load_lds(16B), linear LDS,
// 4 waves 2x2, 16x16x32 bf16 MFMA, fp32 accum.
template<int OUTBF>
__global__ __launch_bounds__(256) void gemm_bt(const u16* __restrict__ A,
    const u16* __restrict__ Bm, const float* __restrict__ bias,
    void* __restrict__ Cv, int M, int N, int K)
{
  const int tid  = threadIdx.x;
  const int lane = tid & 63, wid = tid >> 6;
  const int l15  = lane & 15, l4 = lane >> 4;
  const int wr   = wid >> 1,  wc = wid & 1;
  const int row0 = blockIdx.y * 128, col0 = blockIdx.x * 128;

  __shared__ u16 As[128 * 64];
  __shared__ u16 Bs[128 * 64];

  float4v acc[4][4];
  #pragma unroll
  for(int m = 0; m < 4; m++)
    #pragma unroll
    for(int n = 0; n < 4; n++) acc[m][n] = (float4v){0.f, 0.f, 0.f, 0.f};

  const int srow = wid * 8 + (lane >> 3);
  const int scol = (lane & 7) * 8;
  const u16* Ag = A  + (size_t)(row0 + srow) * K + scol;
  const u16* Bg = Bm + (size_t)(col0 + srow) * K + scol;
  u16* Asl = As + (wid * 8) * 64;
  u16* Bsl = Bs + (wid * 8) * 64;

  for(int kt = 0; kt < K; kt += 64){
    __syncthreads();
    #pragma unroll
    for(int i = 0; i < 4; i++){
      gload16(Ag + (size_t)i * 32 * K + kt, Asl + i * 32 * 64);
      gload16(Bg + (size_t)i * 32 * K + kt, Bsl + i * 32 * 64);
    }
    __syncthreads();
    #pragma unroll
    for(int kk = 0; kk < 2; kk++){
      short8 af[4], bf[4];
      #pragma unroll
      for(int m = 0; m < 4; m++)
        af[m] = *(const short8*)(As + (wr * 64 + m * 16 + l15) * 64 + kk * 32 + l4 * 8);
      #pragma unroll
      for(int n = 0; n < 4; n++)
        bf[n] = *(const short8*)(Bs + (wc * 64 + n * 16 + l15) * 64 + kk * 32 + l4 * 8);
      #pragma unroll
      for(int m = 0; m < 4; m++)
        #pragma unroll
        for(int n = 0; n < 4; n++)
          acc[m][n] = __builtin_amdgcn_mfma_f32_16x16x32_bf16(af[m], bf[n], acc[m][n], 0, 0, 0);
    }
  }
  #pragma unroll
  for(int m = 0; m < 4; m++){
    #pragma unroll
    for(int n = 0; n < 4; n++){
      int col = col0 + wc * 64 + n * 16 + l15;
      float bv = bias[col];
      #pragma unroll
      for(int j = 0; j < 4; j++){
        int row = row0 + wr * 64 + m * 16 + l4 * 4 + j;
        float v = acc[m][n][j] + bv;
        if(OUTBF) ((u16*)Cv)[(size_t)row * N + col] = f2bf(v);
        else      ((float*)Cv)[(size_t)row * N + col] = v;
      }
    }
  }
}

// ---------------- cluster assign softmax + ck (rotated) / cv (transposed) ----------------
__global__ __launch_bounds__(256) void cluster_kernel(
    const float* __restrict__ x, const float* __restrict__ wasn,
    const u16* __restrict__ qkv, const float* __restrict__ S,
    u16* __restrict__ ckr, u16* __restrict__ vct)
{
  const int bc = blockIdx.x;         // b*64 + c
  const int c = bc & 63, b = bc >> 6;
  const int tid = threadIdx.x;
  const int lane = tid & 63, wv = tid >> 6;
  __shared__ float wgt[64];

  const float* xrow = x + ((size_t)b * T_ + c * 64) * C_;
  float4v wa4[4];
  #pragma unroll
  for(int ch = 0; ch < 4; ch++)
    wa4[ch] = *(const float4v*)(wasn + c * C_ + ch * 256 + lane * 4);

  for(int it = 0; it < 16; it++){
    int t = it * 4 + wv;
    const float* xr = xrow + (size_t)t * C_;
    float p = 0.f;
    #pragma unroll
    for(int ch = 0; ch < 4; ch++){
      float4v xv = *(const float4v*)(xr + ch * 256 + lane * 4);
      p += xv.x * wa4[ch].x + xv.y * wa4[ch].y + xv.z * wa4[ch].z + xv.w * wa4[ch].w;
    }
    p += __shfl_down(p, 32); p += __shfl_down(p, 16); p += __shfl_down(p, 8);
    p += __shfl_down(p, 4);  p += __shfl_down(p, 2);  p += __shfl_down(p, 1);
    if(lane == 0) wgt[t] = p;
  }
  __syncthreads();
  if(wv == 0){
    float v = wgt[lane];
    float mx = v;
    mx = fmaxf(mx, __shfl_xor(mx, 32)); mx = fmaxf(mx, __shfl_xor(mx, 16));
    mx = fmaxf(mx, __shfl_xor(mx, 8));  mx = fmaxf(mx, __shfl_xor(mx, 4));
    mx = fmaxf(mx, __shfl_xor(mx, 2));  mx = fmaxf(mx, __shfl_xor(mx, 1));
    float e = expf(v - mx);
    float sm = e;
    sm += __shfl_xor(sm, 32); sm += __shfl_xor(sm, 16); sm += __shfl_xor(sm, 8);
    sm += __shfl_xor(sm, 4);  sm += __shfl_xor(sm, 2);  sm += __shfl_xor(sm, 1);
    wgt[lane] = e / sm;
  }
  __syncthreads();

  const int d0 = tid * 4;
  float ak[4] = {0, 0, 0, 0}, av[4] = {0, 0, 0, 0};
  const u16* krow = qkv + ((size_t)b * T_ + c * 64) * 3072 + C_ + d0;
  for(int t = 0; t < 64; t++){
    float wt = wgt[t];
    short4v kv = *(const short4v*)(krow + (size_t)t * 3072);
    short4v vv = *(const short4v*)(krow + (size_t)t * 3072 + C_);
    ak[0] += wt * bf2f((u16)kv.x); ak[1] += wt * bf2f((u16)kv.y);
    ak[2] += wt * bf2f((u16)kv.z); ak[3] += wt * bf2f((u16)kv.w);
    av[0] += wt * bf2f((u16)vv.x); av[1] += wt * bf2f((u16)vv.y);
    av[2] += wt * bf2f((u16)vv.z); av[3] += wt * bf2f((u16)vv.w);
  }
  // rotary on ck with pos = c (pairs within head)
  const int dh = d0 & 63, i0 = dh >> 1;
  const float* Sp = S + c * 64;
  float s0 = Sp[i0],     c0 = Sp[32 + i0];
  float s1 = Sp[i0 + 1], c1 = Sp[32 + i0 + 1];
  short4v ck4;
  ck4.x = (short)f2bf(-ak[1] * c0); ck4.y = (short)f2bf(ak[0] * s0);
  ck4.z = (short)f2bf(-ak[3] * c1); ck4.w = (short)f2bf(ak[2] * s1);
  *(short4v*)(ckr + ((size_t)b * NC_ + c) * C_ + d0) = ck4;
  // cv transposed: vct[b][h][d][c]
  const int h = d0 >> 6;
  u16* vp = vct + (((size_t)b * H_ + h) * 64 + dh) * 64 + c;
  #pragma unroll
  for(int i = 0; i < 4; i++) vp[(size_t)i * 64] = f2bf(av[i]);
}

// ---------------- in-place rotary on q and k regions of qkv ----------------
__global__ __launch_bounds__(256) void rotqk_kernel(u16* __restrict__ qkv,
                                                    const float* __restrict__ S){
  int idx = blockIdx.x * 256 + threadIdx.x;   // 2 * 16384 * 128 chunks
  int sel = idx >> 21;                        // 0 = q, 1 = k
  int r = idx & 0x1FFFFF;
  int token = r >> 7;
  int c8 = r & 127;
  int t = token & (T_ - 1);
  int pos = sel ? ((t >> 8) * 4 + (t & 255)) : (t & 255);
  int d0 = c8 * 8;
  int i0 = (d0 & 63) >> 1;
  u16* p = qkv + (size_t)token * 3072 + sel * C_ + d0;
  uint4v vv = *(const uint4v*)p;
  const float* Sp = S + pos * 64;
  uint4v ov;
  #pragma unroll
  for(int q = 0; q < 4; q++){
    u32 w2 = vv[q];
    float e0 = bf2f((u16)(w2 & 0xffffu));
    float e1 = bf2f((u16)(w2 >> 16));
    float sn = Sp[i0 + q], cs = Sp[32 + i0 + q];
    u32 ow = (u32)f2bf(-e1 * cs) | ((u32)f2bf(e0 * sn) << 16);
    ov[q] = ow;
  }
  *(uint4v*)p = ov;
}

// ---------------- V transpose: vt[b,g,h][d][k] ----------------
__global__ __launch_bounds__(256) void vtrans_kernel(const u16* __restrict__ qkv,
                                                     u16* __restrict__ vt){
  const int bid = blockIdx.x;               // b*256 + g*16 + h
  const int h = bid & 15, g = (bid >> 4) & 15, b = bid >> 8;
  const int tid = threadIdx.x;
  __shared__ u16 tile[256 * 80];
  const u16* src = qkv + ((size_t)b * T_ + g * GS_) * 3072 + 2 * C_ + h * 64;
  #pragma unroll
  for(int it = 0; it < 8; it++){
    int ch = it * 256 + tid;
    int k = ch >> 3, dd0 = (ch & 7) * 8;
    *(uint4v*)(tile + k * 80 + dd0) = *(const uint4v*)(src + (size_t)k * 3072 + dd0);
  }
  __syncthreads();
  u32* dst = (u32*)(vt + (size_t)bid * 64 * 256);
  #pragma unroll
  for(int it = 0; it < 32; it++){
    int u = it * 256 + tid;
    int d = u >> 7, k = (u & 127) * 2;
    u32 a  = tile[k * 80 + d];
    u32 bb = tile[(k + 1) * 80 + d];
    dst[u] = a | (bb << 16);
  }
}

// ---------------- attention: 1 block per (b,g,h), 4 waves x 64 q-rows ----------------
__global__ __launch_bounds__(256) void attn_kernel(
    const u16* __restrict__ qkv, const u16* __restrict__ ckr,
    const u16* __restrict__ vct, const u16* __restrict__ vt,
    u16* __restrict__ y)
{
  const int bid = blockIdx.x;
  const int h = bid & 15, g = (bid >> 4) & 15, b = bid >> 8;
  const int tid = threadIdx.x;
  const int lane = tid & 63, wv = tid >> 6;
  const int l15 = lane & 15, l4 = lane >> 4;

  __shared__ u16 pb_all[4][64 * 72];
  u16* pbuf = pb_all[wv];

  const int qrow0 = b * T_ + g * GS_ + wv * 64;
  short8 qa[4][2];
  #pragma unroll
  for(int m = 0; m < 4; m++)
    #pragma unroll
    for(int kk = 0; kk < 2; kk++)
      qa[m][kk] = *(const short8*)(qkv + (size_t)(qrow0 + m * 16 + l15) * 3072
                                   + h * 64 + kk * 32 + l4 * 8);

  float mst[4][4], lst[4][4];
  float4v o[4][4];
  #pragma unroll
  for(int m = 0; m < 4; m++)
    #pragma unroll
    for(int j = 0; j < 4; j++){ mst[m][j] = -1e30f; lst[m][j] = 0.f; }
  #pragma unroll
  for(int m = 0; m < 4; m++)
    #pragma unroll
    for(int n = 0; n < 4; n++) o[m][n] = (float4v){0, 0, 0, 0};

  auto do_tile = [&](const u16* kb, int kstr, const u16* vb, int vstr, int koff, int mode){
    float4v s[4][4];
    #pragma unroll
    for(int m = 0; m < 4; m++)
      #pragma unroll
      for(int n = 0; n < 4; n++) s[m][n] = (float4v){0, 0, 0, 0};
    #pragma unroll
    for(int kk = 0; kk < 2; kk++){
      short8 kf[4];
      #pragma unroll
      for(int n = 0; n < 4; n++)
        kf[n] = *(const short8*)(kb + (size_t)(n * 16 + l15) * kstr + kk * 32 + l4 * 8);
      #pragma unroll
      for(int m = 0; m < 4; m++)
        #pragma unroll
        for(int n = 0; n < 4; n++)
          s[m][n] = __builtin_amdgcn_mfma_f32_16x16x32_bf16(qa[m][kk], kf[n], s[m][n], 0, 0, 0);
    }
    const int climit = g * 4;
    #pragma unroll
    for(int m = 0; m < 4; m++)
      #pragma unroll
      for(int n = 0; n < 4; n++){
        int col = n * 16 + l15;
        #pragma unroll
        for(int j = 0; j < 4; j++){
          float v = s[m][n][j] * 0.125f;
          bool masked = (mode == 2) ? (col >= climit)
                      : (mode == 1) ? (col > m * 16 + l4 * 4 + j) : false;
          s[m][n][j] = masked ? -1e30f : v;
        }
      }
    // online softmax update
    #pragma unroll
    for(int m = 0; m < 4; m++)
      #pragma unroll
      for(int j = 0; j < 4; j++){
        float mx = s[m][0][j];
        #pragma unroll
        for(int n = 1; n < 4; n++) mx = fmaxf(mx, s[m][n][j]);
        mx = fmaxf(mx, __shfl_xor(mx, 1)); mx = fmaxf(mx, __shfl_xor(mx, 2));
        mx = fmaxf(mx, __shfl_xor(mx, 4)); mx = fmaxf(mx, __shfl_xor(mx, 8));
        float mn = fmaxf(mst[m][j], mx);
        float rescale = expf(mst[m][j] - mn);
        mst[m][j] = mn;
        float rs = 0.f;
        #pragma unroll
        for(int n = 0; n < 4; n++){
          float p = expf(s[m][n][j] - mn);
          s[m][n][j] = p;
          rs += p;
        }
        rs += __shfl_xor(rs, 1); rs += __shfl_xor(rs, 2);
        rs += __shfl_xor(rs, 4); rs += __shfl_xor(rs, 8);
        lst[m][j] = lst[m][j] * rescale + rs;
        #pragma unroll
        for(int n = 0; n < 4; n++) o[m][n][j] *= rescale;
      }
    // P -> LDS (bf16) -> A-frags
    #pragma unroll
    for(int m = 0; m < 4; m++)
      #pragma unroll
      for(int n = 0; n < 4; n++)
        #pragma unroll
        for(int j = 0; j < 4; j++)
          pbuf[(m * 16 + l4 * 4 + j) * 72 + n * 16 + l15] = f2bf(s[m][n][j]);
    short8 pa[4][2];
    #pragma unroll
    for(int m = 0; m < 4; m++)
      #pragma unroll
      for(int ks = 0; ks < 2; ks++)
        pa[m][ks] = *(const short8*)(pbuf + (m * 16 + l15) * 72 + ks * 32 + l4 * 8);
    #pragma unroll
    for(int ks = 0; ks < 2; ks++){
      short8 vf[4];
      #pragma unroll
      for(int n = 0; n < 4; n++)
        vf[n] = *(const short8*)(vb + (size_t)(n * 16 + l15) * vstr + koff + ks * 32 + l4 * 8);
      #pragma unroll
      for(int m = 0; m < 4; m++)
        #pragma unroll
        for(int n = 0; n < 4; n++)
          o[m][n] = __builtin_amdgcn_mfma_f32_16x16x32_bf16(pa[m][ks], vf[n], o[m][n], 0, 0, 0);
    }
  };

  if(g > 0)
    do_tile(ckr + (size_t)b * NC_ * C_ + h * 64, C_,
            vct + ((size_t)b * H_ + h) * 64 * 64, 64, 0, 2);
  const u16* klbase = qkv + ((size_t)b * T_ + g * GS_) * 3072 + C_ + h * 64;
  const u16* vtbase = vt + (size_t)bid * 64 * 256;
  for(int kt = 0; kt <= wv; kt++)
    do_tile(klbase + (size_t)kt * 64 * 3072, 3072, vtbase, 256, kt * 64,
            (kt == wv) ? 1 : 0);

  #pragma unroll
  for(int m = 0; m < 4; m++)
    #pragma unroll
    for(int j = 0; j < 4; j++){
      float inv = 1.0f / lst[m][j];
      int row = qrow0 + m * 16 + l4 * 4 + j;
      #pragma unroll
      for(int n = 0; n < 4; n++)
        y[(size_t)row * C_ + h * 64 + n * 16 + l15] = f2bf(o[m][n][j] * inv);
    }
}

// ---------------- launcher ----------------
extern "C" void kernel_launch(void* const* d_in, const int* in_sizes, int n_in,
                              void* d_out, int out_size, void* d_ws, size_t ws_size,
                              hipStream_t stream)
{
  const float* x      = (const float*)d_in[0];
  const float* w_attn = (const float*)d_in[1];
  const float* b_attn = (const float*)d_in[2];
  const float* w_proj = (const float*)d_in[3];
  const float* b_proj = (const float*)d_in[4];
  const float* wasn   = (const float*)d_in[5];
  float* out = (float*)d_out;
  char* ws = (char*)d_ws;

  // workspace layout (bytes)
  u16* qkv  = (u16*)(ws);                    // 100,663,296  bf16 (B,T,3C); q,k rotated in place
  u16* xb   = (u16*)(ws + 100663296);        //  33,554,432  bf16 x; later reused as y
  u16* vt   = (u16*)(ws + 134217728);        //  33,554,432  bf16 [b,g,h][d][k]
  u16* wab  = (u16*)(ws + 167772160);        //   6,291,456
  u16* wpb  = (u16*)(ws + 174063616);        //   2,097,152
  u16* ckr  = (u16*)(ws + 176160768);        //     524,288  rotated cluster keys
  u16* vct  = (u16*)(ws + 176685056);        //     524,288  transposed cluster values
  float* st = (float*)(ws + 177209344);      //      80,896  sinusoid table
  if(ws_size < 177290240) return;

  f2b_kernel<<<16384, 256, 0, stream>>>(x, xb, 4194304);
  f2b_kernel<<<3072, 256, 0, stream>>>(w_attn, wab, 786432);
  f2b_kernel<<<1024, 256, 0, stream>>>(w_proj, wpb, 262144);
  stab_kernel<<<316, 64, 0, stream>>>(st);
  gemm_bt<1><<<dim3(24, 128), 256, 0, stream>>>(xb, wab, b_attn, (void*)qkv, 16384, 3072, 1024);
  cluster_kernel<<<256, 256, 0, stream>>>(x, wasn, qkv, st, ckr, vct);
  rotqk_kernel<<<16384, 256, 0, stream>>>(qkv, st);
  vtrans_kernel<<<1024, 256, 0, stream>>>(qkv, vt);
  attn_kernel<<<1024, 256, 0, stream>>>(qkv, ckr, vct, vt, xb /*y*/);
  gemm_bt<0><<<dim3(8, 128), 256, 0, stream>>>(xb, wpb, b_proj, (void*)out, 16384, 1024, 1024);
}

// Round 2
// 375.532 us; speedup vs baseline: 1.1500x; 1.1500x over previous
//
#include <hip/hip_runtime.h>
#include <stdint.h>

typedef unsigned short u16;
typedef unsigned int   u32;
typedef __attribute__((ext_vector_type(8))) short short8;
typedef __attribute__((ext_vector_type(4))) short short4v;
typedef __attribute__((ext_vector_type(4))) float float4v;
typedef __attribute__((ext_vector_type(4))) u32   uint4v;

#define B_  4
#define T_  4096
#define C_  1024
#define H_  16
#define G_  16
#define GS_ 256
#define NC_ 64

static __device__ __forceinline__ u16 f2bf(float f){
  union{float f; u32 u;} c; c.f = f;
  return (u16)((c.u + 0x7fffu + ((c.u >> 16) & 1u)) >> 16);
}
static __device__ __forceinline__ float bf2f(u16 u){
  union{u32 u; float f;} c; c.u = ((u32)u) << 16; return c.f;
}
static __device__ __forceinline__ void gload16(const void* g, void* l){
  __builtin_amdgcn_global_load_lds((__attribute__((address_space(1))) void*)g,
                                   (__attribute__((address_space(3))) void*)l, 16, 0, 0);
}

// ---------------- fp32 -> bf16 convert ----------------
__global__ __launch_bounds__(256) void f2b_kernel(const float* __restrict__ s,
                                                  u16* __restrict__ d, int n4){
  int i = blockIdx.x * 256 + threadIdx.x;
  if(i >= n4) return;
  float4v v = *(const float4v*)(s + (size_t)i * 4);
  short4v o;
  o.x = (short)f2bf(v.x); o.y = (short)f2bf(v.y);
  o.z = (short)f2bf(v.z); o.w = (short)f2bf(v.w);
  *(short4v*)(d + (size_t)i * 4) = o;
}

// ---------------- sinusoidal table S[pos][d], pos<316, d<64 ----------------
__global__ void stab_kernel(float* __restrict__ S){
  int pos = blockIdx.x, d = threadIdx.x;
  int j = d >> 1;
  float div = expf((float)(2 * j) * (-0.14391156831212787f)); // -ln(10000)/64
  float ang = (float)pos * div;
  S[pos * 64 + d] = (d & 1) ? cosf(ang) : sinf(ang);
}

// ================= 8-phase 256x256 GEMM: C[M,N] = A[M,K]*B[N,K]^T + bias =================
// T1 XCD swizzle + T2 LDS xor-swizzle (both-sides via pre-swizzled global src)
// + T3/T4 phase-split with counted vmcnt(4) + T5 setprio. 8 waves (2Mx4N),
// BK=64 split in two k-halves; LDS [dbuf][khalf][256][32] u16 = 128 KiB.
template<int OUTBF>
__global__ __launch_bounds__(512, 1) void gemm8p(const u16* __restrict__ A,
    const u16* __restrict__ Bm, const float* __restrict__ bias,
    void* __restrict__ Cv, int M, int N, int K, int nbn)
{
  __shared__ u16 sA[2][2][256][32];
  __shared__ u16 sB[2][2][256][32];
  const int tid = threadIdx.x;
  const int lane = tid & 63, w = tid >> 6;
  const int l15 = lane & 15, l4 = lane >> 4;
  const int wr = w >> 2, wc = w & 3;

  // T1: bijective XCD swizzle (gridDim.x % 8 == 0 guaranteed by launcher)
  const int cpx = gridDim.x >> 3;
  const int bid = blockIdx.x;
  const int swz = (bid & 7) * cpx + (bid >> 3);
  const int bm = swz / nbn, bn = swz - bm * nbn;
  const int row0 = bm * 256, col0 = bn * 256;

  float4v acc[8][4];
  #pragma unroll
  for(int m = 0; m < 8; m++)
    #pragma unroll
    for(int n = 0; n < 4; n++) acc[m][n] = (float4v){0.f, 0.f, 0.f, 0.f};

  const int srow = lane >> 2;      // 0..15 within a 16-row chunk
  const int sslot = lane & 3;

  // stage one half-tile (256 rows x 32 kcols) with inverse-swizzled global src
  auto stageHalf = [&](const u16* G, int grow0, u16* dstPlane, int ktOff){
    #pragma unroll
    for(int l = 0; l < 2; l++){
      int r = w * 32 + l * 16 + srow;
      int ss = sslot ^ ((r >> 1) & 3);
      gload16(G + (size_t)(grow0 + r) * K + ktOff + ss * 8,
              dstPlane + (w * 32 + l * 16) * 32);
    }
  };
  auto ldsReadA = [&](int d, int kk, int mh, short8* af){
    #pragma unroll
    for(int i = 0; i < 4; i++){
      int r = wr * 128 + (mh * 4 + i) * 16 + l15;
      int slot = l4 ^ ((r >> 1) & 3);
      af[i] = *(const short8*)&sA[d][kk][r][slot * 8];
    }
  };
  auto ldsReadB = [&](int d, int kk, short8* bf){
    #pragma unroll
    for(int i = 0; i < 4; i++){
      int r = wc * 64 + i * 16 + l15;
      int slot = l4 ^ ((r >> 1) & 3);
      bf[i] = *(const short8*)&sB[d][kk][r][slot * 8];
    }
  };
  auto mfma16 = [&](int mh, short8* af, short8* bf){
    __builtin_amdgcn_s_setprio(1);
    #pragma unroll
    for(int i = 0; i < 4; i++)
      #pragma unroll
      for(int n = 0; n < 4; n++)
        acc[mh * 4 + i][n] = __builtin_amdgcn_mfma_f32_16x16x32_bf16(af[i], bf[n], acc[mh * 4 + i][n], 0, 0, 0);
    __builtin_amdgcn_s_setprio(0);
  };

  // prologue: tile 0 into buf 0 (order: Ak0, Bk0, Ak1, Bk1)
  stageHalf(A,  row0, &sA[0][0][0][0], 0);
  stageHalf(Bm, col0, &sB[0][0][0][0], 0);
  stageHalf(A,  row0, &sA[0][1][0][0], 32);
  stageHalf(Bm, col0, &sB[0][1][0][0], 32);
  asm volatile("s_waitcnt vmcnt(4)" ::: "memory");
  __builtin_amdgcn_s_barrier();

  const int nT = K >> 6;
  for(int t = 0; t < nT; t++){
    const int d = t & 1, dn = d ^ 1;
    const int ktN = (t + 1) << 6;
    const bool pf = (t + 1 < nT);
    short8 af[4], bf[4];

    // phase 1: kk=0, mh=0
    ldsReadA(d, 0, 0, af); ldsReadB(d, 0, bf);
    if(pf) stageHalf(A, row0, &sA[dn][0][0][0], ktN);
    __builtin_amdgcn_s_barrier();
    mfma16(0, af, bf);
    __builtin_amdgcn_s_barrier();

    // phase 2: kk=0, mh=1 (reuse bf)
    ldsReadA(d, 0, 1, af);
    if(pf) stageHalf(Bm, col0, &sB[dn][0][0][0], ktN);
    __builtin_amdgcn_s_barrier();
    mfma16(1, af, bf);
    if(pf) asm volatile("s_waitcnt vmcnt(4)" ::: "memory");
    else   asm volatile("s_waitcnt vmcnt(0)" ::: "memory");
    __builtin_amdgcn_s_barrier();

    // phase 3: kk=1, mh=0
    ldsReadA(d, 1, 0, af); ldsReadB(d, 1, bf);
    if(pf) stageHalf(A, row0, &sA[dn][1][0][0], ktN + 32);
    __builtin_amdgcn_s_barrier();
    mfma16(0, af, bf);
    __builtin_amdgcn_s_barrier();

    // phase 4: kk=1, mh=1 (reuse bf)
    ldsReadA(d, 1, 1, af);
    if(pf) stageHalf(Bm, col0, &sB[dn][1][0][0], ktN + 32);
    __builtin_amdgcn_s_barrier();
    mfma16(1, af, bf);
    if(pf) asm volatile("s_waitcnt vmcnt(4)" ::: "memory");
    __builtin_amdgcn_s_barrier();
  }

  // epilogue: bias + store
  #pragma unroll
  for(int m = 0; m < 8; m++){
    #pragma unroll
    for(int n = 0; n < 4; n++){
      int col = col0 + wc * 64 + n * 16 + l15;
      float bv = bias[col];
      #pragma unroll
      for(int j = 0; j < 4; j++){
        int row = row0 + wr * 128 + m * 16 + l4 * 4 + j;
        float v = acc[m][n][j] + bv;
        if(OUTBF) ((u16*)Cv)[(size_t)row * N + col] = f2bf(v);
        else      ((float*)Cv)[(size_t)row * N + col] = v;
      }
    }
  }
}

// ---------------- cluster assign softmax + ck (rotated) / cv (transposed) ----------------
__global__ __launch_bounds__(256) void cluster_kernel(
    const float* __restrict__ x, const float* __restrict__ wasn,
    const u16* __restrict__ qkv, const float* __restrict__ S,
    u16* __restrict__ ckr, u16* __restrict__ vct)
{
  const int bc = blockIdx.x;         // b*64 + c
  const int c = bc & 63, b = bc >> 6;
  const int tid = threadIdx.x;
  const int lane = tid & 63, wv = tid >> 6;
  __shared__ float wgt[64];

  const float* xrow = x + ((size_t)b * T_ + c * 64) * C_;
  float4v wa4[4];
  #pragma unroll
  for(int ch = 0; ch < 4; ch++)
    wa4[ch] = *(const float4v*)(wasn + c * C_ + ch * 256 + lane * 4);

  for(int it = 0; it < 16; it++){
    int t = it * 4 + wv;
    const float* xr = xrow + (size_t)t * C_;
    float p = 0.f;
    #pragma unroll
    for(int ch = 0; ch < 4; ch++){
      float4v xv = *(const float4v*)(xr + ch * 256 + lane * 4);
      p += xv.x * wa4[ch].x + xv.y * wa4[ch].y + xv.z * wa4[ch].z + xv.w * wa4[ch].w;
    }
    p += __shfl_down(p, 32); p += __shfl_down(p, 16); p += __shfl_down(p, 8);
    p += __shfl_down(p, 4);  p += __shfl_down(p, 2);  p += __shfl_down(p, 1);
    if(lane == 0) wgt[t] = p;
  }
  __syncthreads();
  if(wv == 0){
    float v = wgt[lane];
    float mx = v;
    mx = fmaxf(mx, __shfl_xor(mx, 32)); mx = fmaxf(mx, __shfl_xor(mx, 16));
    mx = fmaxf(mx, __shfl_xor(mx, 8));  mx = fmaxf(mx, __shfl_xor(mx, 4));
    mx = fmaxf(mx, __shfl_xor(mx, 2));  mx = fmaxf(mx, __shfl_xor(mx, 1));
    float e = expf(v - mx);
    float sm = e;
    sm += __shfl_xor(sm, 32); sm += __shfl_xor(sm, 16); sm += __shfl_xor(sm, 8);
    sm += __shfl_xor(sm, 4);  sm += __shfl_xor(sm, 2);  sm += __shfl_xor(sm, 1);
    wgt[lane] = e / sm;
  }
  __syncthreads();

  const int d0 = tid * 4;
  float ak[4] = {0, 0, 0, 0}, av[4] = {0, 0, 0, 0};
  const u16* krow = qkv + ((size_t)b * T_ + c * 64) * 3072 + C_ + d0;
  for(int t = 0; t < 64; t++){
    float wt = wgt[t];
    short4v kv = *(const short4v*)(krow + (size_t)t * 3072);
    short4v vv = *(const short4v*)(krow + (size_t)t * 3072 + C_);
    ak[0] += wt * bf2f((u16)kv.x); ak[1] += wt * bf2f((u16)kv.y);
    ak[2] += wt * bf2f((u16)kv.z); ak[3] += wt * bf2f((u16)kv.w);
    av[0] += wt * bf2f((u16)vv.x); av[1] += wt * bf2f((u16)vv.y);
    av[2] += wt * bf2f((u16)vv.z); av[3] += wt * bf2f((u16)vv.w);
  }
  // rotary on ck with pos = c (pairs within head)
  const int dh = d0 & 63, i0 = dh >> 1;
  const float* Sp = S + c * 64;
  float s0 = Sp[i0],     c0 = Sp[32 + i0];
  float s1 = Sp[i0 + 1], c1 = Sp[32 + i0 + 1];
  short4v ck4;
  ck4.x = (short)f2bf(-ak[1] * c0); ck4.y = (short)f2bf(ak[0] * s0);
  ck4.z = (short)f2bf(-ak[3] * c1); ck4.w = (short)f2bf(ak[2] * s1);
  *(short4v*)(ckr + ((size_t)b * NC_ + c) * C_ + d0) = ck4;
  // cv transposed: vct[b][h][d][c]
  const int h = d0 >> 6;
  u16* vp = vct + (((size_t)b * H_ + h) * 64 + dh) * 64 + c;
  #pragma unroll
  for(int i = 0; i < 4; i++) vp[(size_t)i * 64] = f2bf(av[i]);
}

// ---------------- in-place rotary on q and k regions of qkv ----------------
__global__ __launch_bounds__(256) void rotqk_kernel(u16* __restrict__ qkv,
                                                    const float* __restrict__ S){
  int idx = blockIdx.x * 256 + threadIdx.x;   // 2 * 16384 * 128 chunks
  int sel = idx >> 21;                        // 0 = q, 1 = k
  int r = idx & 0x1FFFFF;
  int token = r >> 7;
  int c8 = r & 127;
  int t = token & (T_ - 1);
  int pos = sel ? ((t >> 8) * 4 + (t & 255)) : (t & 255);
  int d0 = c8 * 8;
  int i0 = (d0 & 63) >> 1;
  u16* p = qkv + (size_t)token * 3072 + sel * C_ + d0;
  uint4v vv = *(const uint4v*)p;
  const float* Sp = S + pos * 64;
  uint4v ov;
  #pragma unroll
  for(int q = 0; q < 4; q++){
    u32 w2 = vv[q];
    float e0 = bf2f((u16)(w2 & 0xffffu));
    float e1 = bf2f((u16)(w2 >> 16));
    float sn = Sp[i0 + q], cs = Sp[32 + i0 + q];
    u32 ow = (u32)f2bf(-e1 * cs) | ((u32)f2bf(e0 * sn) << 16);
    ov[q] = ow;
  }
  *(uint4v*)p = ov;
}

// ---------------- V transpose: vt[b,g,h][d][k] ----------------
__global__ __launch_bounds__(256) void vtrans_kernel(const u16* __restrict__ qkv,
                                                     u16* __restrict__ vt){
  const int bid = blockIdx.x;               // b*256 + g*16 + h
  const int h = bid & 15, g = (bid >> 4) & 15, b = bid >> 8;
  const int tid = threadIdx.x;
  __shared__ u16 tile[256 * 80];
  const u16* src = qkv + ((size_t)b * T_ + g * GS_) * 3072 + 2 * C_ + h * 64;
  #pragma unroll
  for(int it = 0; it < 8; it++){
    int ch = it * 256 + tid;
    int k = ch >> 3, dd0 = (ch & 7) * 8;
    *(uint4v*)(tile + k * 80 + dd0) = *(const uint4v*)(src + (size_t)k * 3072 + dd0);
  }
  __syncthreads();
  u32* dst = (u32*)(vt + (size_t)bid * 64 * 256);
  #pragma unroll
  for(int it = 0; it < 32; it++){
    int u = it * 256 + tid;
    int d = u >> 7, k = (u & 127) * 2;
    u32 a  = tile[k * 80 + d];
    u32 bb = tile[(k + 1) * 80 + d];
    dst[u] = a | (bb << 16);
  }
}

// ---------------- attention: 1 block per (b,g,h), 4 waves x 64 q-rows ----------------
__global__ __launch_bounds__(256) void attn_kernel(
    const u16* __restrict__ qkv, const u16* __restrict__ ckr,
    const u16* __restrict__ vct, const u16* __restrict__ vt,
    u16* __restrict__ y)
{
  const int bid = blockIdx.x;
  const int h = bid & 15, g = (bid >> 4) & 15, b = bid >> 8;
  const int tid = threadIdx.x;
  const int lane = tid & 63, wv = tid >> 6;
  const int l15 = lane & 15, l4 = lane >> 4;

  __shared__ u16 pb_all[4][64 * 72];
  u16* pbuf = pb_all[wv];

  const int qrow0 = b * T_ + g * GS_ + wv * 64;
  short8 qa[4][2];
  #pragma unroll
  for(int m = 0; m < 4; m++)
    #pragma unroll
    for(int kk = 0; kk < 2; kk++)
      qa[m][kk] = *(const short8*)(qkv + (size_t)(qrow0 + m * 16 + l15) * 3072
                                   + h * 64 + kk * 32 + l4 * 8);

  float mst[4][4], lst[4][4];
  float4v o[4][4];
  #pragma unroll
  for(int m = 0; m < 4; m++)
    #pragma unroll
    for(int j = 0; j < 4; j++){ mst[m][j] = -1e30f; lst[m][j] = 0.f; }
  #pragma unroll
  for(int m = 0; m < 4; m++)
    #pragma unroll
    for(int n = 0; n < 4; n++) o[m][n] = (float4v){0, 0, 0, 0};

  auto do_tile = [&](const u16* kb, int kstr, const u16* vb, int vstr, int koff, int mode){
    float4v s[4][4];
    #pragma unroll
    for(int m = 0; m < 4; m++)
      #pragma unroll
      for(int n = 0; n < 4; n++) s[m][n] = (float4v){0, 0, 0, 0};
    #pragma unroll
    for(int kk = 0; kk < 2; kk++){
      short8 kf[4];
      #pragma unroll
      for(int n = 0; n < 4; n++)
        kf[n] = *(const short8*)(kb + (size_t)(n * 16 + l15) * kstr + kk * 32 + l4 * 8);
      #pragma unroll
      for(int m = 0; m < 4; m++)
        #pragma unroll
        for(int n = 0; n < 4; n++)
          s[m][n] = __builtin_amdgcn_mfma_f32_16x16x32_bf16(qa[m][kk], kf[n], s[m][n], 0, 0, 0);
    }
    const int climit = g * 4;
    #pragma unroll
    for(int m = 0; m < 4; m++)
      #pragma unroll
      for(int n = 0; n < 4; n++){
        int col = n * 16 + l15;
        #pragma unroll
        for(int j = 0; j < 4; j++){
          float v = s[m][n][j] * 0.125f;
          bool masked = (mode == 2) ? (col >= climit)
                      : (mode == 1) ? (col > m * 16 + l4 * 4 + j) : false;
          s[m][n][j] = masked ? -1e30f : v;
        }
      }
    // online softmax update
    #pragma unroll
    for(int m = 0; m < 4; m++)
      #pragma unroll
      for(int j = 0; j < 4; j++){
        float mx = s[m][0][j];
        #pragma unroll
        for(int n = 1; n < 4; n++) mx = fmaxf(mx, s[m][n][j]);
        mx = fmaxf(mx, __shfl_xor(mx, 1)); mx = fmaxf(mx, __shfl_xor(mx, 2));
        mx = fmaxf(mx, __shfl_xor(mx, 4)); mx = fmaxf(mx, __shfl_xor(mx, 8));
        float mn = fmaxf(mst[m][j], mx);
        float rescale = expf(mst[m][j] - mn);
        mst[m][j] = mn;
        float rs = 0.f;
        #pragma unroll
        for(int n = 0; n < 4; n++){
          float p = expf(s[m][n][j] - mn);
          s[m][n][j] = p;
          rs += p;
        }
        rs += __shfl_xor(rs, 1); rs += __shfl_xor(rs, 2);
        rs += __shfl_xor(rs, 4); rs += __shfl_xor(rs, 8);
        lst[m][j] = lst[m][j] * rescale + rs;
        #pragma unroll
        for(int n = 0; n < 4; n++) o[m][n][j] *= rescale;
      }
    // P -> LDS (bf16) -> A-frags
    #pragma unroll
    for(int m = 0; m < 4; m++)
      #pragma unroll
      for(int n = 0; n < 4; n++)
        #pragma unroll
        for(int j = 0; j < 4; j++)
          pbuf[(m * 16 + l4 * 4 + j) * 72 + n * 16 + l15] = f2bf(s[m][n][j]);
    short8 pa[4][2];
    #pragma unroll
    for(int m = 0; m < 4; m++)
      #pragma unroll
      for(int ks = 0; ks < 2; ks++)
        pa[m][ks] = *(const short8*)(pbuf + (m * 16 + l15) * 72 + ks * 32 + l4 * 8);
    #pragma unroll
    for(int ks = 0; ks < 2; ks++){
      short8 vf[4];
      #pragma unroll
      for(int n = 0; n < 4; n++)
        vf[n] = *(const short8*)(vb + (size_t)(n * 16 + l15) * vstr + koff + ks * 32 + l4 * 8);
      #pragma unroll
      for(int m = 0; m < 4; m++)
        #pragma unroll
        for(int n = 0; n < 4; n++)
          o[m][n] = __builtin_amdgcn_mfma_f32_16x16x32_bf16(pa[m][ks], vf[n], o[m][n], 0, 0, 0);
    }
  };

  if(g > 0)
    do_tile(ckr + (size_t)b * NC_ * C_ + h * 64, C_,
            vct + ((size_t)b * H_ + h) * 64 * 64, 64, 0, 2);
  const u16* klbase = qkv + ((size_t)b * T_ + g * GS_) * 3072 + C_ + h * 64;
  const u16* vtbase = vt + (size_t)bid * 64 * 256;
  for(int kt = 0; kt <= wv; kt++)
    do_tile(klbase + (size_t)kt * 64 * 3072, 3072, vtbase, 256, kt * 64,
            (kt == wv) ? 1 : 0);

  #pragma unroll
  for(int m = 0; m < 4; m++)
    #pragma unroll
    for(int j = 0; j < 4; j++){
      float inv = 1.0f / lst[m][j];
      int row = qrow0 + m * 16 + l4 * 4 + j;
      #pragma unroll
      for(int n = 0; n < 4; n++)
        y[(size_t)row * C_ + h * 64 + n * 16 + l15] = f2bf(o[m][n][j] * inv);
    }
}

// ---------------- launcher ----------------
extern "C" void kernel_launch(void* const* d_in, const int* in_sizes, int n_in,
                              void* d_out, int out_size, void* d_ws, size_t ws_size,
                              hipStream_t stream)
{
  const float* x      = (const float*)d_in[0];
  const float* w_attn = (const float*)d_in[1];
  const float* b_attn = (const float*)d_in[2];
  const float* w_proj = (const float*)d_in[3];
  const float* b_proj = (const float*)d_in[4];
  const float* wasn   = (const float*)d_in[5];
  float* out = (float*)d_out;
  char* ws = (char*)d_ws;

  // workspace layout (bytes)
  u16* qkv  = (u16*)(ws);                    // 100,663,296  bf16 (B,T,3C); q,k rotated in place
  u16* xb   = (u16*)(ws + 100663296);        //  33,554,432  bf16 x; later reused as y
  u16* vt   = (u16*)(ws + 134217728);        //  33,554,432  bf16 [b,g,h][d][k]
  u16* wab  = (u16*)(ws + 167772160);        //   6,291,456
  u16* wpb  = (u16*)(ws + 174063616);        //   2,097,152
  u16* ckr  = (u16*)(ws + 176160768);        //     524,288  rotated cluster keys
  u16* vct  = (u16*)(ws + 176685056);        //     524,288  transposed cluster values
  float* st = (float*)(ws + 177209344);      //      80,896  sinusoid table
  if(ws_size < 177290240) return;

  f2b_kernel<<<16384, 256, 0, stream>>>(x, xb, 4194304);
  f2b_kernel<<<3072, 256, 0, stream>>>(w_attn, wab, 786432);
  f2b_kernel<<<1024, 256, 0, stream>>>(w_proj, wpb, 262144);
  stab_kernel<<<316, 64, 0, stream>>>(st);
  gemm8p<1><<<768, 512, 0, stream>>>(xb, wab, b_attn, (void*)qkv, 16384, 3072, 1024, 12);
  cluster_kernel<<<256, 256, 0, stream>>>(x, wasn, qkv, st, ckr, vct);
  rotqk_kernel<<<16384, 256, 0, stream>>>(qkv, st);
  vtrans_kernel<<<1024, 256, 0, stream>>>(qkv, vt);
  attn_kernel<<<1024, 256, 0, stream>>>(qkv, ckr, vct, vt, xb /*y*/);
  gemm8p<0><<<256, 512, 0, stream>>>(xb, wpb, b_proj, (void*)out, 16384, 1024, 1024, 4);
}